// Round 5
// baseline (2806.217 us; speedup 1.0000x reference)
//
#include <hip/hip_runtime.h>
#include <math.h>

#define BB 64
#define TT 128
#define II 4096
#define HH 1024
#define NG 4096   // 4*H
#define K0 2048   // [ha | ca]
#define K1 3072   // [ha | hb | cb]

typedef __attribute__((ext_vector_type(8))) short short8;
typedef __attribute__((ext_vector_type(4))) float f32x4;
typedef __attribute__((ext_vector_type(4))) unsigned short ushort4v;
typedef __attribute__((ext_vector_type(8))) unsigned short ushort8v;

__device__ __forceinline__ unsigned short f2bf(float f){
  union { float f; unsigned u; } v; v.f = f;
  unsigned r = v.u + 0x7fffu + ((v.u >> 16) & 1u);   // RNE
  return (unsigned short)(r >> 16);
}
__device__ __forceinline__ float bf2f(unsigned short u){
  union { float f; unsigned u; } v; v.u = ((unsigned)u) << 16;
  return v.f;
}
__device__ __forceinline__ float sigm(float x){ return 1.f/(1.f + expf(-x)); }

// fragment-major index for state matrices (rows b=0..63, cols k):
// chunk = (k>>5)*4 + (b>>4); lane = (b&15) | (((k>>3)&3)<<4); elem = k&7.
// Lane l of an MFMA A-fragment (row=l&15, k=(l>>4)*8+e) reads 16 contiguous bytes,
// consecutive lanes contiguous -> coalesced global->reg fragment loads, no LDS.
__device__ __forceinline__ int fidx(int bb, int k){
  return (((k >> 5)*4 + (bb >> 4))*64 + ((bb & 15) | (((k >> 3) & 3) << 4)))*8 + (k & 7);
}

// ---------------- conversion / layout kernels ----------------

__global__ void conv_x(const float* __restrict__ in, unsigned short* __restrict__ outb){
  const size_t i = ((size_t)blockIdx.x*256 + threadIdx.x)*4;
  f32x4 v = *(const f32x4*)(&in[i]);
  ushort4v o; o[0]=f2bf(v[0]); o[1]=f2bf(v[1]); o[2]=f2bf(v[2]); o[3]=f2bf(v[3]);
  *(ushort4v*)(&outb[i]) = o;
}

// Wx0 (4,H,I) -> Wil[n'=4h+g][i], bf16 row-major (for gemm_xz0)
__global__ void build_Wx0il(const float* __restrict__ Wx0, unsigned short* __restrict__ Wil){
  const int row = blockIdx.y;
  const int c4 = (blockIdx.x*256 + threadIdx.x)*4;
  const int g = row & 3, h = row >> 2;
  f32x4 v = *(const f32x4*)(&Wx0[((size_t)(g*HH + h))*II + c4]);
  ushort4v o; o[0]=f2bf(v[0]); o[1]=f2bf(v[1]); o[2]=f2bf(v[2]); o[3]=f2bf(v[3]);
  *(ushort4v*)(&Wil[(size_t)row*II + c4]) = o;
}

// W0f: fragment-major weight for phase A. Source row n (gate row 4*hid+g), col k in [0,K0):
//   k<1024 -> Uh0[g][hid][k]; else Vc0[jj][hid][k-1024] (0 for g==2), jj = (g==3)?2:g.
// Frag layout: chunk=(n>>4)*(K0/32)+(k>>5); lane=(n&15)|(((k>>3)&3)<<4); elem=k&7.
__global__ void build_W0f(const float* __restrict__ Uh0, const float* __restrict__ Vc0,
                          unsigned short* __restrict__ Wf){
  const int n0 = blockIdx.y*16, kb = blockIdx.x*128;
  const int nr = threadIdx.x & 15, kc = threadIdx.x >> 4;
  const int n = n0 + nr, k8 = kb + kc*8;
  const int g = n & 3, hid = n >> 2;
  float v[8];
  if (k8 < HH){
    const float* src = &Uh0[((size_t)(g*HH+hid))*HH + k8];
    #pragma unroll
    for (int e=0;e<8;e++) v[e]=src[e];
  } else if (g == 2){
    #pragma unroll
    for (int e=0;e<8;e++) v[e]=0.f;
  } else {
    const int jj = (g==3)?2:g;
    const float* src = &Vc0[((size_t)(jj*HH+hid))*HH + (k8-HH)];
    #pragma unroll
    for (int e=0;e<8;e++) v[e]=src[e];
  }
  ushort8v o;
  #pragma unroll
  for (int e=0;e<8;e++) o[e]=f2bf(v[e]);
  const int chunk = (n>>4)*(K0/32) + (k8>>5);
  const int lanew = nr | (((k8>>3)&3)<<4);
  *(ushort8v*)(&Wf[((size_t)chunk*64 + lanew)*8]) = o;
}

// W1f: same for phase B, K1 = [Wx1 | Uh1 | Vc1/0]
__global__ void build_W1f(const float* __restrict__ Wx1, const float* __restrict__ Uh1,
                          const float* __restrict__ Vc1, unsigned short* __restrict__ Wf){
  const int n0 = blockIdx.y*16, kb = blockIdx.x*128;
  const int nr = threadIdx.x & 15, kc = threadIdx.x >> 4;
  const int n = n0 + nr, k8 = kb + kc*8;
  const int g = n & 3, hid = n >> 2;
  float v[8];
  if (k8 < HH){
    const float* src = &Wx1[((size_t)(g*HH+hid))*HH + k8];
    #pragma unroll
    for (int e=0;e<8;e++) v[e]=src[e];
  } else if (k8 < 2*HH){
    const float* src = &Uh1[((size_t)(g*HH+hid))*HH + (k8-HH)];
    #pragma unroll
    for (int e=0;e<8;e++) v[e]=src[e];
  } else if (g == 2){
    #pragma unroll
    for (int e=0;e<8;e++) v[e]=0.f;
  } else {
    const int jj = (g==3)?2:g;
    const float* src = &Vc1[((size_t)(jj*HH+hid))*HH + (k8-2*HH)];
    #pragma unroll
    for (int e=0;e<8;e++) v[e]=src[e];
  }
  ushort8v o;
  #pragma unroll
  for (int e=0;e<8;e++) o[e]=f2bf(v[e]);
  const int chunk = (n>>4)*(K1/32) + (k8>>5);
  const int lanew = nr | (((k8>>3)&3)<<4);
  *(ushort8v*)(&Wf[((size_t)chunk*64 + lanew)*8]) = o;
}

__global__ void init_state2(const float* __restrict__ h0, const float* __restrict__ c0,
  float* __restrict__ ca_f, float* __restrict__ cb_f,
  unsigned short* __restrict__ A0w, unsigned short* __restrict__ A1w){
  const int idx = blockIdx.x*256 + threadIdx.x;   // < 65536
  const int b = idx >> 10, k = idx & 1023;
  const float ha = h0[idx], ca = c0[idx];
  const float hb = h0[BB*HH + idx], cb = c0[BB*HH + idx];
  ca_f[idx]=ca; cb_f[idx]=cb;
  A0w[fidx(b, k)]        = f2bf(ha);
  A0w[fidx(b, HH + k)]   = f2bf(ca);
  A1w[fidx(b, HH + k)]   = f2bf(hb);
  A1w[fidx(b, 2*HH + k)] = f2bf(cb);
}

// ---------------- big precompute GEMM: XZ0 = x . Wx0il^T + b0 ----------------
// C layout [t*BB + b][n] so each step reads one contiguous 512 KB slab.
__global__ __launch_bounds__(256) void gemm_xz0(
  const unsigned short* __restrict__ A, const unsigned short* __restrict__ Wt,
  const float* __restrict__ b0, unsigned short* __restrict__ C)
{
  __shared__ __align__(16) unsigned short Asm[128*72];
  __shared__ __align__(16) unsigned short Wsm[128*72];
  const int tid = threadIdx.x, lane = tid & 63, w = tid >> 6;
  const int wr = w >> 1, wc = w & 1;
  const int m0 = blockIdx.y * 128, n0 = blockIdx.x * 128;
  const int rA = tid >> 3, c8 = (tid & 7) * 8;

  f32x4 acc[4][4];
  #pragma unroll
  for (int i=0;i<4;i++)
    #pragma unroll
    for (int j=0;j<4;j++) acc[i][j] = f32x4{0.f,0.f,0.f,0.f};

  ushort8v pa[4], pw[4];
  #pragma unroll
  for (int s=0;s<4;s++){
    pa[s] = *(const ushort8v*)(&A [(size_t)(m0 + rA + 32*s)*II + c8]);
    pw[s] = *(const ushort8v*)(&Wt[(size_t)(n0 + rA + 32*s)*II + c8]);
  }
  for (int kt = 0; kt < II; kt += 64) {
    __syncthreads();
    #pragma unroll
    for (int s=0;s<4;s++){
      *(ushort8v*)(&Asm[(rA+32*s)*72 + c8]) = pa[s];
      *(ushort8v*)(&Wsm[(rA+32*s)*72 + c8]) = pw[s];
    }
    __syncthreads();
    if (kt + 64 < II){
      #pragma unroll
      for (int s=0;s<4;s++){
        pa[s] = *(const ushort8v*)(&A [(size_t)(m0 + rA + 32*s)*II + kt + 64 + c8]);
        pw[s] = *(const ushort8v*)(&Wt[(size_t)(n0 + rA + 32*s)*II + kt + 64 + c8]);
      }
    }
    #pragma unroll
    for (int ks=0; ks<2; ks++){
      const int kk = ks*32 + (lane>>4)*8;
      short8 af[4], bfv[4];
      #pragma unroll
      for (int rt=0; rt<4; rt++)
        af[rt] = *(const short8*)(&Asm[(wr*64 + rt*16 + (lane&15))*72 + kk]);
      #pragma unroll
      for (int ct=0; ct<4; ct++)
        bfv[ct] = *(const short8*)(&Wsm[(wc*64 + ct*16 + (lane&15))*72 + kk]);
      #pragma unroll
      for (int rt=0; rt<4; rt++)
        #pragma unroll
        for (int ct=0; ct<4; ct++)
          acc[rt][ct] = __builtin_amdgcn_mfma_f32_16x16x32_bf16(af[rt], bfv[ct], acc[rt][ct], 0,0,0);
    }
  }
  #pragma unroll
  for (int rt=0; rt<4; rt++){
    #pragma unroll
    for (int ct=0; ct<4; ct++){
      const int n = n0 + wc*64 + ct*16 + (lane&15);
      const float bias = b0[(n&3)*HH + (n>>2)];
      #pragma unroll
      for (int r=0;r<4;r++){
        const int m = m0 + wr*64 + rt*16 + (lane>>4)*4 + r;
        const int row = (m & 127)*BB + (m >> 7);   // [t][b] layout
        C[(size_t)row*NG + n] = f2bf(acc[rt][ct][r] + bias);
      }
    }
  }
}

// ---------------- fused step kernel: phase A(t) || phase B(t-1) ----------------
// grid 256 x 256: blocks 0..127 phase A (32 gate cols each), 128..255 phase B.
// 1 block/CU. A(t) dep A(t-1); B(t-1) dep A(t-1),B(t-2) -> independent within launch.
// GEMM: barrier-free, pure global->reg fragment loads. Each A-fragment (state) is
// loaded once and feeds 2 MFMAs (2 col-groups) -> state re-read traffic halved vs 16-col.

template<int KC>   // KC = K/32 total k-chunks
__device__ __forceinline__ void gemm_frag32(const unsigned short* __restrict__ Af,
                                            const unsigned short* __restrict__ Wfull,
                                            int cg0, int wave, int lane, f32x4 (&acc)[4][2])
{
  constexpr int NJ = KC/4;   // k-chunks per wave
  const unsigned short* abase = Af + ((size_t)(wave*NJ*4)*64 + lane)*8;
  const unsigned short* wb0 = Wfull + ((size_t)((cg0+0)*KC + wave*NJ)*64 + lane)*8;
  const unsigned short* wb1 = Wfull + ((size_t)((cg0+1)*KC + wave*NJ)*64 + lane)*8;
  short8 wf[NJ][2];
  #pragma unroll
  for (int j = 0; j < NJ; ++j){
    wf[j][0] = *(const short8*)(wb0 + (size_t)(j*64)*8);
    wf[j][1] = *(const short8*)(wb1 + (size_t)(j*64)*8);
  }
  short8 buf[4][4];             // 4-deep ring, fully unrolled -> static indices
  #pragma unroll
  for (int j = 0; j < NJ + 3; ++j) {
    if (j < NJ) {
      #pragma unroll
      for (int m = 0; m < 4; ++m)
        buf[j & 3][m] = *(const short8*)(abase + (size_t)((j*4 + m)*64)*8);
    }
    if (j >= 3) {
      const int jc = j - 3;
      #pragma unroll
      for (int m = 0; m < 4; ++m){
        acc[m][0] = __builtin_amdgcn_mfma_f32_16x16x32_bf16(buf[jc & 3][m], wf[jc][0], acc[m][0], 0, 0, 0);
        acc[m][1] = __builtin_amdgcn_mfma_f32_16x16x32_bf16(buf[jc & 3][m], wf[jc][1], acc[m][1], 0, 0, 0);
      }
    }
  }
}

__global__ __launch_bounds__(256, 1) void lstm_step_fused(
  const unsigned short* __restrict__ A0r, unsigned short* __restrict__ A0n,
  const unsigned short* __restrict__ A1r, unsigned short* __restrict__ A1w,
  const unsigned short* __restrict__ W0f, const unsigned short* __restrict__ W1f,
  const unsigned short* __restrict__ XZ0, const float* __restrict__ b1v,
  float* __restrict__ ca_f, float* __restrict__ cb_f,
  float* __restrict__ out, int t)
{
  __shared__ float preSm[4][64][33];    // 33-pad: conflict-light cross-wave reduce
  const int tid = threadIdx.x, lane = tid & 63, wave = tid >> 6;
  float* outp = out + (size_t)BB*TT*HH;

  if (blockIdx.x < 128) {
    // ---- phase A(t): pre = [ha|ca] . W0^T (+XZ0; b0 folded into XZ0) ----
    if (t >= TT) return;
    const int blk = blockIdx.x, n0 = blk*32;
    f32x4 acc[4][2];
    #pragma unroll
    for (int m=0;m<4;m++){ acc[m][0] = f32x4{0.f,0.f,0.f,0.f}; acc[m][1] = f32x4{0.f,0.f,0.f,0.f}; }
    gemm_frag32<K0/32>(A0r, W0f, blk*2, wave, lane, acc);
    #pragma unroll
    for (int m=0;m<4;m++)
      #pragma unroll
      for (int c=0;c<2;c++)
        #pragma unroll
        for (int r=0;r<4;r++)
          preSm[wave][m*16 + (lane>>4)*4 + r][c*16 + (lane & 15)] = acc[m][c][r];
    __syncthreads();
    #pragma unroll
    for (int e=0;e<2;++e){
      const int idx = tid + e*256;
      const int b = idx >> 3, kl = idx & 7;      // 64 batches x 8 hidden units
      const int kh = blk*8 + kl;
      float p0=0.f,p1=0.f,p2=0.f,p3=0.f;
      #pragma unroll
      for (int w2=0; w2<4; ++w2){
        p0 += preSm[w2][b][4*kl+0];
        p1 += preSm[w2][b][4*kl+1];
        p2 += preSm[w2][b][4*kl+2];
        p3 += preSm[w2][b][4*kl+3];
      }
      ushort4v xz = *(const ushort4v*)(&XZ0[((size_t)t*BB + b)*NG + n0 + 4*kl]);
      p0 += bf2f(xz[0]); p1 += bf2f(xz[1]); p2 += bf2f(xz[2]); p3 += bf2f(xz[3]);
      const float ig = sigm(p0), fg = sigm(p1), gg = tanhf(p2), og = sigm(p3);
      const int si = b*HH + kh;
      const float cn = fg*ca_f[si] + ig*gg;
      const float hn = og*tanhf(cn);
      ca_f[si] = cn;
      const unsigned short h16 = f2bf(hn), c16 = f2bf(cn);
      A0n[fidx(b, kh)]      = h16;
      A0n[fidx(b, HH + kh)] = c16;
      A1w[fidx(b, kh)]      = h16;       // stage ha(t) for B(t) next launch
      if (t == TT-1){ outp[si] = hn; outp[2*BB*HH + si] = cn; }
    }
  } else {
    // ---- phase B(t-1): pre = [ha|hb|cb] . W1^T + b1 ----
    if (t == 0) return;
    const int blk = blockIdx.x - 128, n0 = blk*32;
    const int tb = t - 1;
    f32x4 acc[4][2];
    #pragma unroll
    for (int m=0;m<4;m++){ acc[m][0] = f32x4{0.f,0.f,0.f,0.f}; acc[m][1] = f32x4{0.f,0.f,0.f,0.f}; }
    gemm_frag32<K1/32>(A1r, W1f, blk*2, wave, lane, acc);
    #pragma unroll
    for (int m=0;m<4;m++)
      #pragma unroll
      for (int c=0;c<2;c++)
        #pragma unroll
        for (int r=0;r<4;r++)
          preSm[wave][m*16 + (lane>>4)*4 + r][c*16 + (lane & 15)] = acc[m][c][r];
    __syncthreads();
    #pragma unroll
    for (int e=0;e<2;++e){
      const int idx = tid + e*256;
      const int b = idx >> 3, kl = idx & 7;
      const int kh = blk*8 + kl;
      float p0 = b1v[kh], p1 = b1v[HH+kh], p2 = b1v[2*HH+kh], p3 = b1v[3*HH+kh];
      #pragma unroll
      for (int w2=0; w2<4; ++w2){
        p0 += preSm[w2][b][4*kl+0];
        p1 += preSm[w2][b][4*kl+1];
        p2 += preSm[w2][b][4*kl+2];
        p3 += preSm[w2][b][4*kl+3];
      }
      const float ig = sigm(p0), fg = sigm(p1), gg = tanhf(p2), og = sigm(p3);
      const int si = b*HH + kh;
      const float cn = fg*cb_f[si] + ig*gg;
      const float hn = og*tanhf(cn);
      cb_f[si] = cn;
      A1w[fidx(b, HH + kh)]   = f2bf(hn);
      A1w[fidx(b, 2*HH + kh)] = f2bf(cn);
      out[((size_t)b*TT + tb)*HH + kh] = hn;
      if (tb == TT-1){ outp[BB*HH + si] = hn; outp[3*BB*HH + si] = cn; }
    }
  }
}

// ---------------- host ----------------

extern "C" void kernel_launch(void* const* d_in, const int* in_sizes, int n_in,
                              void* d_out, int out_size, void* d_ws, size_t ws_size,
                              hipStream_t stream)
{
  (void)in_sizes; (void)n_in; (void)out_size; (void)ws_size;
  const float* x   = (const float*)d_in[0];
  const float* h0  = (const float*)d_in[1];
  const float* c0  = (const float*)d_in[2];
  const float* Wx0 = (const float*)d_in[3];
  const float* Uh0 = (const float*)d_in[4];
  const float* Vc0 = (const float*)d_in[5];
  const float* b0  = (const float*)d_in[6];
  const float* Wx1 = (const float*)d_in[7];
  const float* Uh1 = (const float*)d_in[8];
  const float* Vc1 = (const float*)d_in[9];
  const float* b1  = (const float*)d_in[10];
  float* out = (float*)d_out;

  char* ws = (char*)d_ws;
  size_t off = 0;
  auto alloc = [&](size_t bytes) { char* p = ws + off; off += (bytes + 255) & ~(size_t)255; return p; };
  unsigned short* x_bf  = (unsigned short*)alloc((size_t)BB*TT*II*2);
  unsigned short* Wx0il = (unsigned short*)alloc((size_t)NG*II*2);
  unsigned short* XZ0   = (unsigned short*)alloc((size_t)BB*TT*NG*2);
  unsigned short* W0f   = (unsigned short*)alloc((size_t)NG*K0*2);
  unsigned short* W1f   = (unsigned short*)alloc((size_t)NG*K1*2);
  unsigned short* A0b[2] = { (unsigned short*)alloc((size_t)BB*K0*2), (unsigned short*)alloc((size_t)BB*K0*2) };
  unsigned short* A1b[2] = { (unsigned short*)alloc((size_t)BB*K1*2), (unsigned short*)alloc((size_t)BB*K1*2) };
  float* ca_f = (float*)alloc((size_t)BB*HH*4);
  float* cb_f = (float*)alloc((size_t)BB*HH*4);

  conv_x<<<32768, 256, 0, stream>>>(x, x_bf);
  build_Wx0il<<<dim3(4,4096), 256, 0, stream>>>(Wx0, Wx0il);
  build_W0f<<<dim3(K0/128, NG/16), 256, 0, stream>>>(Uh0, Vc0, W0f);
  build_W1f<<<dim3(K1/128, NG/16), 256, 0, stream>>>(Wx1, Uh1, Vc1, W1f);
  init_state2<<<256, 256, 0, stream>>>(h0, c0, ca_f, cb_f, A0b[0], A1b[0]);
  gemm_xz0<<<dim3(32,64), 256, 0, stream>>>(x_bf, Wx0il, b0, XZ0);

  // fused time loop: launch t runs A(t) || B(t-1); t=0 A-only, t=TT B-only.
  for (int t = 0; t <= TT; ++t) {
    const int q = t & 1;
    lstm_step_fused<<<256, 256, 0, stream>>>(
        A0b[q], A0b[q^1],          // A reads [ha|ca](t-1), writes (t)
        A1b[q^1], A1b[q],          // B reads [ha(t-1)|hb|cb](t-2..t-1); A+B write A1b[q]
        W0f, W1f, XZ0, b1, ca_f, cb_f, out, t);
  }
}

// Round 6
// 2274.760 us; speedup vs baseline: 1.2336x; 1.2336x over previous
//
#include <hip/hip_runtime.h>
#include <math.h>

#define BB 64
#define TT 128
#define II 4096
#define HH 1024
#define NG 4096   // 4*H
#define K0 2048   // [ha | ca]
#define K1 3072   // [ha | hb | cb]

typedef __attribute__((ext_vector_type(8))) short short8;
typedef __attribute__((ext_vector_type(4))) float f32x4;
typedef __attribute__((ext_vector_type(4))) unsigned short ushort4v;
typedef __attribute__((ext_vector_type(8))) unsigned short ushort8v;

__device__ __forceinline__ unsigned short f2bf(float f){
  union { float f; unsigned u; } v; v.f = f;
  unsigned r = v.u + 0x7fffu + ((v.u >> 16) & 1u);   // RNE
  return (unsigned short)(r >> 16);
}
__device__ __forceinline__ float bf2f(unsigned short u){
  union { float f; unsigned u; } v; v.u = ((unsigned)u) << 16;
  return v.f;
}
__device__ __forceinline__ float sigm(float x){ return 1.f/(1.f + expf(-x)); }

// fragment-major index for state matrices (rows b=0..63, cols k):
// chunk = (k>>5)*4 + (b>>4); lane = (b&15) | (((k>>3)&3)<<4); elem = k&7.
// Lane l of an MFMA A-fragment (row=l&15, k=(l>>4)*8+e) reads 16 contiguous bytes,
// consecutive lanes contiguous -> coalesced global->reg fragment loads, no LDS.
__device__ __forceinline__ int fidx(int bb, int k){
  return (((k >> 5)*4 + (bb >> 4))*64 + ((bb & 15) | (((k >> 3) & 3) << 4)))*8 + (k & 7);
}

// ---------------- conversion / layout kernels ----------------

__global__ void conv_x(const float* __restrict__ in, unsigned short* __restrict__ outb){
  const size_t i = ((size_t)blockIdx.x*256 + threadIdx.x)*4;
  f32x4 v = *(const f32x4*)(&in[i]);
  ushort4v o; o[0]=f2bf(v[0]); o[1]=f2bf(v[1]); o[2]=f2bf(v[2]); o[3]=f2bf(v[3]);
  *(ushort4v*)(&outb[i]) = o;
}

// Wx0 (4,H,I) -> Wil[n'=4h+g][i], bf16 row-major (for gemm_xz0)
__global__ void build_Wx0il(const float* __restrict__ Wx0, unsigned short* __restrict__ Wil){
  const int row = blockIdx.y;
  const int c4 = (blockIdx.x*256 + threadIdx.x)*4;
  const int g = row & 3, h = row >> 2;
  f32x4 v = *(const f32x4*)(&Wx0[((size_t)(g*HH + h))*II + c4]);
  ushort4v o; o[0]=f2bf(v[0]); o[1]=f2bf(v[1]); o[2]=f2bf(v[2]); o[3]=f2bf(v[3]);
  *(ushort4v*)(&Wil[(size_t)row*II + c4]) = o;
}

// W0f: fragment-major weight for phase A. Source row n (gate row 4*hid+g), col k in [0,K0):
//   k<1024 -> Uh0[g][hid][k]; else Vc0[jj][hid][k-1024] (0 for g==2), jj = (g==3)?2:g.
// Frag layout: chunk=(n>>4)*(K0/32)+(k>>5); lane=(n&15)|(((k>>3)&3)<<4); elem=k&7.
__global__ void build_W0f(const float* __restrict__ Uh0, const float* __restrict__ Vc0,
                          unsigned short* __restrict__ Wf){
  const int n0 = blockIdx.y*16, kb = blockIdx.x*128;
  const int nr = threadIdx.x & 15, kc = threadIdx.x >> 4;
  const int n = n0 + nr, k8 = kb + kc*8;
  const int g = n & 3, hid = n >> 2;
  float v[8];
  if (k8 < HH){
    const float* src = &Uh0[((size_t)(g*HH+hid))*HH + k8];
    #pragma unroll
    for (int e=0;e<8;e++) v[e]=src[e];
  } else if (g == 2){
    #pragma unroll
    for (int e=0;e<8;e++) v[e]=0.f;
  } else {
    const int jj = (g==3)?2:g;
    const float* src = &Vc0[((size_t)(jj*HH+hid))*HH + (k8-HH)];
    #pragma unroll
    for (int e=0;e<8;e++) v[e]=src[e];
  }
  ushort8v o;
  #pragma unroll
  for (int e=0;e<8;e++) o[e]=f2bf(v[e]);
  const int chunk = (n>>4)*(K0/32) + (k8>>5);
  const int lanew = nr | (((k8>>3)&3)<<4);
  *(ushort8v*)(&Wf[((size_t)chunk*64 + lanew)*8]) = o;
}

// W1f: same for phase B, K1 = [Wx1 | Uh1 | Vc1/0]
__global__ void build_W1f(const float* __restrict__ Wx1, const float* __restrict__ Uh1,
                          const float* __restrict__ Vc1, unsigned short* __restrict__ Wf){
  const int n0 = blockIdx.y*16, kb = blockIdx.x*128;
  const int nr = threadIdx.x & 15, kc = threadIdx.x >> 4;
  const int n = n0 + nr, k8 = kb + kc*8;
  const int g = n & 3, hid = n >> 2;
  float v[8];
  if (k8 < HH){
    const float* src = &Wx1[((size_t)(g*HH+hid))*HH + k8];
    #pragma unroll
    for (int e=0;e<8;e++) v[e]=src[e];
  } else if (k8 < 2*HH){
    const float* src = &Uh1[((size_t)(g*HH+hid))*HH + (k8-HH)];
    #pragma unroll
    for (int e=0;e<8;e++) v[e]=src[e];
  } else if (g == 2){
    #pragma unroll
    for (int e=0;e<8;e++) v[e]=0.f;
  } else {
    const int jj = (g==3)?2:g;
    const float* src = &Vc1[((size_t)(jj*HH+hid))*HH + (k8-2*HH)];
    #pragma unroll
    for (int e=0;e<8;e++) v[e]=src[e];
  }
  ushort8v o;
  #pragma unroll
  for (int e=0;e<8;e++) o[e]=f2bf(v[e]);
  const int chunk = (n>>4)*(K1/32) + (k8>>5);
  const int lanew = nr | (((k8>>3)&3)<<4);
  *(ushort8v*)(&Wf[((size_t)chunk*64 + lanew)*8]) = o;
}

__global__ void init_state2(const float* __restrict__ h0, const float* __restrict__ c0,
  float* __restrict__ ca_f, float* __restrict__ cb_f,
  unsigned short* __restrict__ A0w, unsigned short* __restrict__ A1w){
  const int idx = blockIdx.x*256 + threadIdx.x;   // < 65536
  const int b = idx >> 10, k = idx & 1023;
  const float ha = h0[idx], ca = c0[idx];
  const float hb = h0[BB*HH + idx], cb = c0[BB*HH + idx];
  ca_f[idx]=ca; cb_f[idx]=cb;
  A0w[fidx(b, k)]        = f2bf(ha);
  A0w[fidx(b, HH + k)]   = f2bf(ca);
  A1w[fidx(b, HH + k)]   = f2bf(hb);
  A1w[fidx(b, 2*HH + k)] = f2bf(cb);
}

// ---------------- big precompute GEMM: XZ0 = x . Wx0il^T + b0 ----------------
// C layout [t*BB + b][n] so each step reads one contiguous 512 KB slab.
__global__ __launch_bounds__(256) void gemm_xz0(
  const unsigned short* __restrict__ A, const unsigned short* __restrict__ Wt,
  const float* __restrict__ b0, unsigned short* __restrict__ C)
{
  __shared__ __align__(16) unsigned short Asm[128*72];
  __shared__ __align__(16) unsigned short Wsm[128*72];
  const int tid = threadIdx.x, lane = tid & 63, w = tid >> 6;
  const int wr = w >> 1, wc = w & 1;
  const int m0 = blockIdx.y * 128, n0 = blockIdx.x * 128;
  const int rA = tid >> 3, c8 = (tid & 7) * 8;

  f32x4 acc[4][4];
  #pragma unroll
  for (int i=0;i<4;i++)
    #pragma unroll
    for (int j=0;j<4;j++) acc[i][j] = f32x4{0.f,0.f,0.f,0.f};

  ushort8v pa[4], pw[4];
  #pragma unroll
  for (int s=0;s<4;s++){
    pa[s] = *(const ushort8v*)(&A [(size_t)(m0 + rA + 32*s)*II + c8]);
    pw[s] = *(const ushort8v*)(&Wt[(size_t)(n0 + rA + 32*s)*II + c8]);
  }
  for (int kt = 0; kt < II; kt += 64) {
    __syncthreads();
    #pragma unroll
    for (int s=0;s<4;s++){
      *(ushort8v*)(&Asm[(rA+32*s)*72 + c8]) = pa[s];
      *(ushort8v*)(&Wsm[(rA+32*s)*72 + c8]) = pw[s];
    }
    __syncthreads();
    if (kt + 64 < II){
      #pragma unroll
      for (int s=0;s<4;s++){
        pa[s] = *(const ushort8v*)(&A [(size_t)(m0 + rA + 32*s)*II + kt + 64 + c8]);
        pw[s] = *(const ushort8v*)(&Wt[(size_t)(n0 + rA + 32*s)*II + kt + 64 + c8]);
      }
    }
    #pragma unroll
    for (int ks=0; ks<2; ks++){
      const int kk = ks*32 + (lane>>4)*8;
      short8 af[4], bfv[4];
      #pragma unroll
      for (int rt=0; rt<4; rt++)
        af[rt] = *(const short8*)(&Asm[(wr*64 + rt*16 + (lane&15))*72 + kk]);
      #pragma unroll
      for (int ct=0; ct<4; ct++)
        bfv[ct] = *(const short8*)(&Wsm[(wc*64 + ct*16 + (lane&15))*72 + kk]);
      #pragma unroll
      for (int rt=0; rt<4; rt++)
        #pragma unroll
        for (int ct=0; ct<4; ct++)
          acc[rt][ct] = __builtin_amdgcn_mfma_f32_16x16x32_bf16(af[rt], bfv[ct], acc[rt][ct], 0,0,0);
    }
  }
  #pragma unroll
  for (int rt=0; rt<4; rt++){
    #pragma unroll
    for (int ct=0; ct<4; ct++){
      const int n = n0 + wc*64 + ct*16 + (lane&15);
      const float bias = b0[(n&3)*HH + (n>>2)];
      #pragma unroll
      for (int r=0;r<4;r++){
        const int m = m0 + wr*64 + rt*16 + (lane>>4)*4 + r;
        const int row = (m & 127)*BB + (m >> 7);   // [t][b] layout
        C[(size_t)row*NG + n] = f2bf(acc[rt][ct][r] + bias);
      }
    }
  }
}

// ---------------- fused step kernel: phase A(t) || phase B(t-1) ----------------
// grid 256 x 512 threads (8 waves): blocks 0..127 phase A (32 cols each),
// 128..255 phase B (32 cols each). 1 block/CU, 2 waves/SIMD (launch_bounds(512,2)).
// K split 8-way across waves; cross-wave reduce through LDS (8 partials).
// GEMM: barrier-free, pure global->reg fragment loads; each state fragment feeds 2 MFMAs.

template<int KC, int NW>   // KC = K/32 total k-chunks, NW = waves
__device__ __forceinline__ void gemm_frag32(const unsigned short* __restrict__ Af,
                                            const unsigned short* __restrict__ Wfull,
                                            int cg0, int wave, int lane, f32x4 (&acc)[4][2])
{
  constexpr int NJ = KC/NW;   // k-chunks per wave
  const unsigned short* abase = Af + ((size_t)(wave*NJ*4)*64 + lane)*8;
  const unsigned short* wb0 = Wfull + ((size_t)((cg0+0)*KC + wave*NJ)*64 + lane)*8;
  const unsigned short* wb1 = Wfull + ((size_t)((cg0+1)*KC + wave*NJ)*64 + lane)*8;
  short8 wf[NJ][2];
  #pragma unroll
  for (int j = 0; j < NJ; ++j){
    wf[j][0] = *(const short8*)(wb0 + (size_t)(j*64)*8);
    wf[j][1] = *(const short8*)(wb1 + (size_t)(j*64)*8);
  }
  short8 buf[4][4];             // 4-deep ring, fully unrolled -> static indices
  #pragma unroll
  for (int j = 0; j < NJ + 3; ++j) {
    if (j < NJ) {
      #pragma unroll
      for (int m = 0; m < 4; ++m)
        buf[j & 3][m] = *(const short8*)(abase + (size_t)((j*4 + m)*64)*8);
    }
    if (j >= 3) {
      const int jc = j - 3;
      #pragma unroll
      for (int m = 0; m < 4; ++m){
        acc[m][0] = __builtin_amdgcn_mfma_f32_16x16x32_bf16(buf[jc & 3][m], wf[jc][0], acc[m][0], 0, 0, 0);
        acc[m][1] = __builtin_amdgcn_mfma_f32_16x16x32_bf16(buf[jc & 3][m], wf[jc][1], acc[m][1], 0, 0, 0);
      }
    }
  }
}

__global__ __launch_bounds__(512, 2) void lstm_step_fused(
  const unsigned short* __restrict__ A0r, unsigned short* __restrict__ A0n,
  const unsigned short* __restrict__ A1r, unsigned short* __restrict__ A1w,
  const unsigned short* __restrict__ W0f, const unsigned short* __restrict__ W1f,
  const unsigned short* __restrict__ XZ0, const float* __restrict__ b1v,
  float* __restrict__ ca_f, float* __restrict__ cb_f,
  float* __restrict__ out, int t)
{
  __shared__ float preSm[8][64][33];    // 67.6 KB; pad 33: conflict-light reduce
  const int tid = threadIdx.x, lane = tid & 63, wave = tid >> 6;
  const int b = tid >> 3, kl = tid & 7;        // epilogue mapping: 64 x 8
  float* outp = out + (size_t)BB*TT*HH;

  if (blockIdx.x < 128) {
    // ---- phase A(t): pre = [ha|ca] . W0^T (+XZ0; b0 folded into XZ0) ----
    if (t >= TT) return;
    const int blk = blockIdx.x, n0 = blk*32;
    f32x4 acc[4][2];
    #pragma unroll
    for (int m=0;m<4;m++){ acc[m][0] = f32x4{0.f,0.f,0.f,0.f}; acc[m][1] = f32x4{0.f,0.f,0.f,0.f}; }
    gemm_frag32<K0/32, 8>(A0r, W0f, blk*2, wave, lane, acc);
    #pragma unroll
    for (int m=0;m<4;m++)
      #pragma unroll
      for (int c=0;c<2;c++)
        #pragma unroll
        for (int r=0;r<4;r++)
          preSm[wave][m*16 + (lane>>4)*4 + r][c*16 + (lane & 15)] = acc[m][c][r];
    __syncthreads();
    {
      const int kh = blk*8 + kl;
      float p0=0.f,p1=0.f,p2=0.f,p3=0.f;
      #pragma unroll
      for (int w2=0; w2<8; ++w2){
        p0 += preSm[w2][b][4*kl+0];
        p1 += preSm[w2][b][4*kl+1];
        p2 += preSm[w2][b][4*kl+2];
        p3 += preSm[w2][b][4*kl+3];
      }
      ushort4v xz = *(const ushort4v*)(&XZ0[((size_t)t*BB + b)*NG + n0 + 4*kl]);
      p0 += bf2f(xz[0]); p1 += bf2f(xz[1]); p2 += bf2f(xz[2]); p3 += bf2f(xz[3]);
      const float ig = sigm(p0), fg = sigm(p1), gg = tanhf(p2), og = sigm(p3);
      const int si = b*HH + kh;
      const float cn = fg*ca_f[si] + ig*gg;
      const float hn = og*tanhf(cn);
      ca_f[si] = cn;
      const unsigned short h16 = f2bf(hn), c16 = f2bf(cn);
      A0n[fidx(b, kh)]      = h16;
      A0n[fidx(b, HH + kh)] = c16;
      A1w[fidx(b, kh)]      = h16;       // stage ha(t) for B(t) next launch
      if (t == TT-1){ outp[si] = hn; outp[2*BB*HH + si] = cn; }
    }
  } else {
    // ---- phase B(t-1): pre = [ha|hb|cb] . W1^T + b1 ----
    if (t == 0) return;
    const int blk = blockIdx.x - 128, n0 = blk*32;
    const int tb = t - 1;
    f32x4 acc[4][2];
    #pragma unroll
    for (int m=0;m<4;m++){ acc[m][0] = f32x4{0.f,0.f,0.f,0.f}; acc[m][1] = f32x4{0.f,0.f,0.f,0.f}; }
    gemm_frag32<K1/32, 8>(A1r, W1f, blk*2, wave, lane, acc);
    #pragma unroll
    for (int m=0;m<4;m++)
      #pragma unroll
      for (int c=0;c<2;c++)
        #pragma unroll
        for (int r=0;r<4;r++)
          preSm[wave][m*16 + (lane>>4)*4 + r][c*16 + (lane & 15)] = acc[m][c][r];
    __syncthreads();
    {
      const int kh = blk*8 + kl;
      float p0 = b1v[kh], p1 = b1v[HH+kh], p2 = b1v[2*HH+kh], p3 = b1v[3*HH+kh];
      #pragma unroll
      for (int w2=0; w2<8; ++w2){
        p0 += preSm[w2][b][4*kl+0];
        p1 += preSm[w2][b][4*kl+1];
        p2 += preSm[w2][b][4*kl+2];
        p3 += preSm[w2][b][4*kl+3];
      }
      const float ig = sigm(p0), fg = sigm(p1), gg = tanhf(p2), og = sigm(p3);
      const int si = b*HH + kh;
      const float cn = fg*cb_f[si] + ig*gg;
      const float hn = og*tanhf(cn);
      cb_f[si] = cn;
      A1w[fidx(b, HH + kh)]   = f2bf(hn);
      A1w[fidx(b, 2*HH + kh)] = f2bf(cn);
      out[((size_t)b*TT + tb)*HH + kh] = hn;
      if (tb == TT-1){ outp[BB*HH + si] = hn; outp[3*BB*HH + si] = cn; }
    }
  }
}

// ---------------- host ----------------

extern "C" void kernel_launch(void* const* d_in, const int* in_sizes, int n_in,
                              void* d_out, int out_size, void* d_ws, size_t ws_size,
                              hipStream_t stream)
{
  (void)in_sizes; (void)n_in; (void)out_size; (void)ws_size;
  const float* x   = (const float*)d_in[0];
  const float* h0  = (const float*)d_in[1];
  const float* c0  = (const float*)d_in[2];
  const float* Wx0 = (const float*)d_in[3];
  const float* Uh0 = (const float*)d_in[4];
  const float* Vc0 = (const float*)d_in[5];
  const float* b0  = (const float*)d_in[6];
  const float* Wx1 = (const float*)d_in[7];
  const float* Uh1 = (const float*)d_in[8];
  const float* Vc1 = (const float*)d_in[9];
  const float* b1  = (const float*)d_in[10];
  float* out = (float*)d_out;

  char* ws = (char*)d_ws;
  size_t off = 0;
  auto alloc = [&](size_t bytes) { char* p = ws + off; off += (bytes + 255) & ~(size_t)255; return p; };
  unsigned short* x_bf  = (unsigned short*)alloc((size_t)BB*TT*II*2);
  unsigned short* Wx0il = (unsigned short*)alloc((size_t)NG*II*2);
  unsigned short* XZ0   = (unsigned short*)alloc((size_t)BB*TT*NG*2);
  unsigned short* W0f   = (unsigned short*)alloc((size_t)NG*K0*2);
  unsigned short* W1f   = (unsigned short*)alloc((size_t)NG*K1*2);
  unsigned short* A0b[2] = { (unsigned short*)alloc((size_t)BB*K0*2), (unsigned short*)alloc((size_t)BB*K0*2) };
  unsigned short* A1b[2] = { (unsigned short*)alloc((size_t)BB*K1*2), (unsigned short*)alloc((size_t)BB*K1*2) };
  float* ca_f = (float*)alloc((size_t)BB*HH*4);
  float* cb_f = (float*)alloc((size_t)BB*HH*4);

  conv_x<<<32768, 256, 0, stream>>>(x, x_bf);
  build_Wx0il<<<dim3(4,4096), 256, 0, stream>>>(Wx0, Wx0il);
  build_W0f<<<dim3(K0/128, NG/16), 256, 0, stream>>>(Uh0, Vc0, W0f);
  build_W1f<<<dim3(K1/128, NG/16), 256, 0, stream>>>(Wx1, Uh1, Vc1, W1f);
  init_state2<<<256, 256, 0, stream>>>(h0, c0, ca_f, cb_f, A0b[0], A1b[0]);
  gemm_xz0<<<dim3(32,64), 256, 0, stream>>>(x_bf, Wx0il, b0, XZ0);

  // fused time loop: launch t runs A(t) || B(t-1); t=0 A-only, t=TT B-only.
  for (int t = 0; t <= TT; ++t) {
    const int q = t & 1;
    lstm_step_fused<<<256, 512, 0, stream>>>(
        A0b[q], A0b[q^1],          // A reads [ha|ca](t-1), writes (t)
        A1b[q^1], A1b[q],          // B reads [ha(t-1)|hb|cb](t-2..t-1); A+B write A1b[q]
        W0f, W1f, XZ0, b1, ca_f, cb_f, out, t);
  }
}